// Round 1
// baseline (8892.151 us; speedup 1.0000x reference)
//
#include <hip/hip_runtime.h>

#define N_NODES 10000
#define N_EDGES 160000
#define E_TOT   170000   // + self loops
#define H1      8
#define C1      120
#define F1      960      // H1*C1

__device__ __forceinline__ unsigned int fenc(float f) {
    unsigned int b = __float_as_uint(f);
    return (b & 0x80000000u) ? ~b : (b | 0x80000000u);
}
__device__ __forceinline__ float fdec(unsigned int u) {
    unsigned int b = (u & 0x80000000u) ? (u & 0x7FFFFFFFu) : ~u;
    return __uint_as_float(b);
}
__device__ __forceinline__ float lrelu(float v) { return v > 0.f ? v : 0.2f * v; }

__device__ __forceinline__ void edge_sd(const int* __restrict__ ei, int e, int& s, int& d) {
    if (e < N_EDGES) { s = ei[e]; d = ei[N_EDGES + e]; }
    else { s = e - N_EDGES; d = s; }
}

// xl1/xr1 = x @ W{l,r} + b{l,r}   (x: [N,4], W: [4,960])
__global__ void transform1(const float* __restrict__ x,
                           const float* __restrict__ Wl, const float* __restrict__ Wr,
                           const float* __restrict__ bl, const float* __restrict__ br,
                           float* __restrict__ xl, float* __restrict__ xr) {
    int idx = blockIdx.x * blockDim.x + threadIdx.x;
    if (idx >= N_NODES * F1) return;
    int node = idx / F1, k = idx - node * F1;
    float x0 = x[node*4+0], x1 = x[node*4+1], x2 = x[node*4+2], x3 = x[node*4+3];
    float l = bl[k] + x0*Wl[k] + x1*Wl[F1 + k] + x2*Wl[2*F1 + k] + x3*Wl[3*F1 + k];
    float r = br[k] + x0*Wr[k] + x1*Wr[F1 + k] + x2*Wr[2*F1 + k] + x3*Wr[3*F1 + k];
    xl[idx] = l;
    xr[idx] = r;
}

// per (edge, head): logit = sum_c att[h,c] * lrelu(xl[src,h,c] + xr[dst,h,c]); atomicMax into m1[dst,h]
__global__ void logits1(const int* __restrict__ ei,
                        const float* __restrict__ xl, const float* __restrict__ xr,
                        const float* __restrict__ att,
                        float* __restrict__ e1, unsigned int* __restrict__ m1) {
    int idx = blockIdx.x * blockDim.x + threadIdx.x;
    if (idx >= E_TOT * H1) return;
    int e = idx >> 3, h = idx & 7;
    int s, d; edge_sd(ei, e, s, d);
    const float4* pl = (const float4*)(xl + (size_t)s * F1 + h * C1);
    const float4* pr = (const float4*)(xr + (size_t)d * F1 + h * C1);
    const float4* pa = (const float4*)(att + h * C1);
    float acc = 0.f;
#pragma unroll
    for (int j = 0; j < C1 / 4; ++j) {
        float4 a = pl[j], b = pr[j], w = pa[j];
        acc += lrelu(a.x + b.x) * w.x + lrelu(a.y + b.y) * w.y
             + lrelu(a.z + b.z) * w.z + lrelu(a.w + b.w) * w.w;
    }
    e1[idx] = acc;
    atomicMax(&m1[d * H1 + h], fenc(acc));
}

__global__ void expsum1(const int* __restrict__ ei,
                        float* __restrict__ e1, const unsigned int* __restrict__ m1,
                        float* __restrict__ d1) {
    int idx = blockIdx.x * blockDim.x + threadIdx.x;
    if (idx >= E_TOT * H1) return;
    int e = idx >> 3, h = idx & 7;
    int s, d; edge_sd(ei, e, s, d);
    float m = fdec(m1[d * H1 + h]);
    float ex = expf(e1[idx] - m);
    e1[idx] = ex;
    atomicAdd(&d1[d * H1 + h], ex);
}

// hbuf[dst,h,:] += alpha * xl[src,h,:]
__global__ void aggregate1(const int* __restrict__ ei,
                           const float* __restrict__ e1, const float* __restrict__ d1,
                           const float* __restrict__ xl, float* __restrict__ hbuf) {
    int idx = blockIdx.x * blockDim.x + threadIdx.x;
    if (idx >= E_TOT * H1) return;
    int e = idx >> 3, h = idx & 7;
    int s, d; edge_sd(ei, e, s, d);
    float alpha = e1[idx] / (d1[d * H1 + h] + 1e-16f);
    const float4* ps = (const float4*)(xl + (size_t)s * F1 + h * C1);
    float* pd = hbuf + (size_t)d * F1 + h * C1;
#pragma unroll
    for (int j = 0; j < C1 / 4; ++j) {
        float4 v = ps[j];
        atomicAdd(&pd[4*j+0], alpha * v.x);
        atomicAdd(&pd[4*j+1], alpha * v.y);
        atomicAdd(&pd[4*j+2], alpha * v.z);
        atomicAdd(&pd[4*j+3], alpha * v.w);
    }
}

__global__ void bias_relu1(float* __restrict__ hbuf, const float* __restrict__ bias) {
    int idx = blockIdx.x * blockDim.x + threadIdx.x;
    if (idx >= N_NODES * F1) return;
    int k = idx % F1;
    hbuf[idx] = fmaxf(hbuf[idx] + bias[k], 0.f);
}

// layer-2 transform: one wave (64 lanes) per node, dot over 960 with W2 [960,4]
__global__ void transform2(const float* __restrict__ hbuf,
                           const float* __restrict__ W2l, const float* __restrict__ W2r,
                           const float* __restrict__ b2l, const float* __restrict__ b2r,
                           float* __restrict__ xl2, float* __restrict__ xr2) {
    int wid = (blockIdx.x * blockDim.x + threadIdx.x) >> 6;
    int lane = threadIdx.x & 63;
    if (wid >= N_NODES) return;
    const float* hp = hbuf + (size_t)wid * F1;
    float al0=0, al1=0, al2=0, al3=0, ar0=0, ar1=0, ar2=0, ar3=0;
#pragma unroll
    for (int j = 0; j < F1 / 64; ++j) {
        int k = lane + 64 * j;
        float hv = hp[k];
        float4 wl = ((const float4*)W2l)[k];
        float4 wr = ((const float4*)W2r)[k];
        al0 += hv * wl.x; al1 += hv * wl.y; al2 += hv * wl.z; al3 += hv * wl.w;
        ar0 += hv * wr.x; ar1 += hv * wr.y; ar2 += hv * wr.z; ar3 += hv * wr.w;
    }
#pragma unroll
    for (int off = 32; off > 0; off >>= 1) {
        al0 += __shfl_down(al0, off, 64); al1 += __shfl_down(al1, off, 64);
        al2 += __shfl_down(al2, off, 64); al3 += __shfl_down(al3, off, 64);
        ar0 += __shfl_down(ar0, off, 64); ar1 += __shfl_down(ar1, off, 64);
        ar2 += __shfl_down(ar2, off, 64); ar3 += __shfl_down(ar3, off, 64);
    }
    if (lane == 0) {
        xl2[wid*4+0] = al0 + b2l[0]; xl2[wid*4+1] = al1 + b2l[1];
        xl2[wid*4+2] = al2 + b2l[2]; xl2[wid*4+3] = al3 + b2l[3];
        xr2[wid*4+0] = ar0 + b2r[0]; xr2[wid*4+1] = ar1 + b2r[1];
        xr2[wid*4+2] = ar2 + b2r[2]; xr2[wid*4+3] = ar3 + b2r[3];
    }
}

__global__ void logits2(const int* __restrict__ ei,
                        const float* __restrict__ xl2, const float* __restrict__ xr2,
                        const float* __restrict__ att2,
                        float* __restrict__ e2, unsigned int* __restrict__ m2) {
    int e = blockIdx.x * blockDim.x + threadIdx.x;
    if (e >= E_TOT) return;
    int s, d; edge_sd(ei, e, s, d);
    float4 a = ((const float4*)xl2)[s];
    float4 b = ((const float4*)xr2)[d];
    float4 w = *(const float4*)att2;
    float acc = lrelu(a.x + b.x) * w.x + lrelu(a.y + b.y) * w.y
              + lrelu(a.z + b.z) * w.z + lrelu(a.w + b.w) * w.w;
    e2[e] = acc;
    atomicMax(&m2[d], fenc(acc));
}

__global__ void expsum2(const int* __restrict__ ei,
                        float* __restrict__ e2, const unsigned int* __restrict__ m2,
                        float* __restrict__ d2) {
    int e = blockIdx.x * blockDim.x + threadIdx.x;
    if (e >= E_TOT) return;
    int s, d; edge_sd(ei, e, s, d);
    float ex = expf(e2[e] - fdec(m2[d]));
    e2[e] = ex;
    atomicAdd(&d2[d], ex);
}

__global__ void aggregate2(const int* __restrict__ ei,
                           const float* __restrict__ e2, const float* __restrict__ d2,
                           const float* __restrict__ xl2, float* __restrict__ out) {
    int e = blockIdx.x * blockDim.x + threadIdx.x;
    if (e >= E_TOT) return;
    int s, d; edge_sd(ei, e, s, d);
    float alpha = e2[e] / (d2[d] + 1e-16f);
    float4 v = ((const float4*)xl2)[s];
    atomicAdd(&out[d*4+0], alpha * v.x);
    atomicAdd(&out[d*4+1], alpha * v.y);
    atomicAdd(&out[d*4+2], alpha * v.z);
    atomicAdd(&out[d*4+3], alpha * v.w);
}

__global__ void bias2add(float* __restrict__ out, const float* __restrict__ bias2) {
    int idx = blockIdx.x * blockDim.x + threadIdx.x;
    if (idx >= N_NODES * 4) return;
    out[idx] += bias2[idx & 3];
}

extern "C" void kernel_launch(void* const* d_in, const int* in_sizes, int n_in,
                              void* d_out, int out_size, void* d_ws, size_t ws_size,
                              hipStream_t stream) {
    const float* x     = (const float*)d_in[0];
    const int*   ei    = (const int*)  d_in[1];
    const float* W1l   = (const float*)d_in[2];
    const float* W1r   = (const float*)d_in[3];
    const float* b1l   = (const float*)d_in[4];
    const float* b1r   = (const float*)d_in[5];
    const float* att1  = (const float*)d_in[6];
    const float* bias1 = (const float*)d_in[7];
    const float* W2l   = (const float*)d_in[8];
    const float* W2r   = (const float*)d_in[9];
    const float* b2l   = (const float*)d_in[10];
    const float* b2r   = (const float*)d_in[11];
    const float* att2  = (const float*)d_in[12];
    const float* bias2 = (const float*)d_in[13];
    float* out = (float*)d_out;

    // workspace carve-up (floats). xr1's buffer is reused as the layer-1
    // aggregation buffer (hbuf) once logits1 is done with xr1.
    float* xl1  = (float*)d_ws;                            // N*F1
    float* xr1  = xl1 + (size_t)N_NODES * F1;              // N*F1 (reused as hbuf)
    float* hbuf = xr1;
    float* e1   = xr1 + (size_t)N_NODES * F1;              // E_TOT*H1
    unsigned int* m1 = (unsigned int*)(e1 + (size_t)E_TOT * H1);  // N*H1
    float* d1   = (float*)(m1 + N_NODES * H1);             // N*H1
    float* xl2  = d1 + N_NODES * H1;                       // N*4
    float* xr2  = xl2 + N_NODES * 4;                       // N*4
    float* e2   = xr2 + N_NODES * 4;                       // E_TOT
    unsigned int* m2 = (unsigned int*)(e2 + E_TOT);        // N
    float* d2   = (float*)(m2 + N_NODES);                  // N

    const int B = 256;

    // zero accumulators (encoded -NaN == 0u is the identity for fenc-atomicMax)
    hipMemsetAsync(m1, 0, N_NODES * H1 * sizeof(unsigned int), stream);
    hipMemsetAsync(d1, 0, N_NODES * H1 * sizeof(float), stream);
    hipMemsetAsync(m2, 0, N_NODES * sizeof(unsigned int), stream);
    hipMemsetAsync(d2, 0, N_NODES * sizeof(float), stream);
    hipMemsetAsync(out, 0, (size_t)N_NODES * 4 * sizeof(float), stream);

    transform1<<<(N_NODES * F1 + B - 1) / B, B, 0, stream>>>(x, W1l, W1r, b1l, b1r, xl1, xr1);
    logits1<<<(E_TOT * H1 + B - 1) / B, B, 0, stream>>>(ei, xl1, xr1, att1, e1, m1);
    expsum1<<<(E_TOT * H1 + B - 1) / B, B, 0, stream>>>(ei, e1, m1, d1);
    // xr1 dead from here; zero it for use as the aggregation buffer
    hipMemsetAsync(hbuf, 0, (size_t)N_NODES * F1 * sizeof(float), stream);
    aggregate1<<<(E_TOT * H1 + B - 1) / B, B, 0, stream>>>(ei, e1, d1, xl1, hbuf);
    bias_relu1<<<(N_NODES * F1 + B - 1) / B, B, 0, stream>>>(hbuf, bias1);
    transform2<<<(N_NODES * 64 + B - 1) / B, B, 0, stream>>>(hbuf, W2l, W2r, b2l, b2r, xl2, xr2);
    logits2<<<(E_TOT + B - 1) / B, B, 0, stream>>>(ei, xl2, xr2, att2, e2, m2);
    expsum2<<<(E_TOT + B - 1) / B, B, 0, stream>>>(ei, e2, m2, d2);
    aggregate2<<<(E_TOT + B - 1) / B, B, 0, stream>>>(ei, e2, d2, xl2, out);
    bias2add<<<(N_NODES * 4 + B - 1) / B, B, 0, stream>>>(out, bias2);
}

// Round 2
// 651.088 us; speedup vs baseline: 13.6574x; 13.6574x over previous
//
#include <hip/hip_runtime.h>

#define N_NODES 10000
#define N_EDGES 160000
#define E_TOT   170000   // + self loops
#define H1      8
#define C1      120
#define F1      960      // H1*C1

__device__ __forceinline__ float lrelu(float v) { return v > 0.f ? v : 0.2f * v; }

__device__ __forceinline__ void edge_sd(const int* __restrict__ ei, int e, int& s, int& d) {
    if (e < N_EDGES) { s = ei[e]; d = ei[N_EDGES + e]; }
    else { s = e - N_EDGES; d = s; }
}
__device__ __forceinline__ int edge_src(const int* __restrict__ ei, int e) {
    return (e < N_EDGES) ? ei[e] : (e - N_EDGES);
}

// ---------------- layer 1 ----------------

// xl1/xr1 = x @ W{l,r} + b{l,r}   (x: [N,4], W: [4,960])
__global__ void transform1(const float* __restrict__ x,
                           const float* __restrict__ Wl, const float* __restrict__ Wr,
                           const float* __restrict__ bl, const float* __restrict__ br,
                           float* __restrict__ xl, float* __restrict__ xr) {
    int idx = blockIdx.x * blockDim.x + threadIdx.x;
    if (idx >= N_NODES * F1) return;
    int node = idx / F1, k = idx - node * F1;
    float x0 = x[node*4+0], x1 = x[node*4+1], x2 = x[node*4+2], x3 = x[node*4+3];
    float l = bl[k] + x0*Wl[k] + x1*Wl[F1 + k] + x2*Wl[2*F1 + k] + x3*Wl[3*F1 + k];
    float r = br[k] + x0*Wr[k] + x1*Wr[F1 + k] + x2*Wr[2*F1 + k] + x3*Wr[3*F1 + k];
    xl[idx] = l;
    xr[idx] = r;
}

// ---------------- CSR build (dst -> incoming edges) ----------------

__global__ void deg_count(const int* __restrict__ ei, int* __restrict__ deg) {
    int e = blockIdx.x * blockDim.x + threadIdx.x;
    if (e >= E_TOT) return;
    int s, d; edge_sd(ei, e, s, d);
    atomicAdd(&deg[d], 1);
}

#define SCAN_T 1024
#define SCAN_I 10   // SCAN_T*SCAN_I = 10240 >= N_NODES
__global__ void scan_rowptr(const int* __restrict__ deg,
                            int* __restrict__ rowptr, int* __restrict__ cur) {
    __shared__ int part[SCAN_T];
    int t = threadIdx.x;
    int base = t * SCAN_I;
    int vals[SCAN_I]; int sum = 0;
#pragma unroll
    for (int i = 0; i < SCAN_I; ++i) {
        int idx = base + i;
        vals[i] = (idx < N_NODES) ? deg[idx] : 0;
        sum += vals[i];
    }
    part[t] = sum;
    __syncthreads();
    for (int off = 1; off < SCAN_T; off <<= 1) {
        int v = (t >= off) ? part[t - off] : 0;
        __syncthreads();
        part[t] += v;
        __syncthreads();
    }
    int run = (t > 0) ? part[t - 1] : 0;  // exclusive base
#pragma unroll
    for (int i = 0; i < SCAN_I; ++i) {
        int idx = base + i;
        if (idx < N_NODES) { rowptr[idx] = run; cur[idx] = run; }
        run += vals[i];
    }
    if (t == SCAN_T - 1) rowptr[N_NODES] = run;
}

__global__ void fill_elist(const int* __restrict__ ei,
                           int* __restrict__ cur, int* __restrict__ elist) {
    int e = blockIdx.x * blockDim.x + threadIdx.x;
    if (e >= E_TOT) return;
    int s, d; edge_sd(ei, e, s, d);
    int pos = atomicAdd(&cur[d], 1);
    elist[pos] = e;
}

// ---------------- layer-1 logits (no atomics) ----------------

__global__ void logits1(const int* __restrict__ ei,
                        const float* __restrict__ xl, const float* __restrict__ xr,
                        const float* __restrict__ att,
                        float* __restrict__ e1) {
    int idx = blockIdx.x * blockDim.x + threadIdx.x;
    if (idx >= E_TOT * H1) return;
    int e = idx >> 3, h = idx & 7;
    int s, d; edge_sd(ei, e, s, d);
    const float4* pl = (const float4*)(xl + (size_t)s * F1 + h * C1);
    const float4* pr = (const float4*)(xr + (size_t)d * F1 + h * C1);
    const float4* pa = (const float4*)(att + h * C1);
    float acc = 0.f;
#pragma unroll
    for (int j = 0; j < C1 / 4; ++j) {
        float4 a = pl[j], b = pr[j], w = pa[j];
        acc += lrelu(a.x + b.x) * w.x + lrelu(a.y + b.y) * w.y
             + lrelu(a.z + b.z) * w.z + lrelu(a.w + b.w) * w.w;
    }
    e1[idx] = acc;
}

// ---------------- layer-1 softmax + aggregate + bias + relu, one wave per (node, head) ----------------

__global__ void softmax_agg1(const int* __restrict__ rowptr, const int* __restrict__ elist,
                             const int* __restrict__ ei,
                             const float* __restrict__ e1, const float* __restrict__ xl,
                             const float* __restrict__ bias,
                             float* __restrict__ hbuf) {
    int gid = (blockIdx.x * blockDim.x + threadIdx.x) >> 6;
    int lane = threadIdx.x & 63;
    if (gid >= N_NODES * H1) return;
    int node = gid >> 3, h = gid & 7;
    int beg = rowptr[node], end = rowptr[node + 1];

    // phase A: running max (lanes over edges)
    float m = -INFINITY;
    for (int i = beg + lane; i < end; i += 64)
        m = fmaxf(m, e1[elist[i] * H1 + h]);
#pragma unroll
    for (int off = 32; off; off >>= 1) m = fmaxf(m, __shfl_xor(m, off, 64));

    // phase B: unnormalized aggregate (lanes over channels), denom computed redundantly per lane
    float2 acc = {0.f, 0.f};
    float ssum = 0.f;
    bool active = lane < 60;  // 60 lanes x float2 = 120 channels
    for (int i = beg; i < end; ++i) {
        int e = elist[i];
        int s = edge_src(ei, e);
        float w = expf(e1[e * H1 + h] - m);
        ssum += w;
        if (active) {
            float2 v = *(const float2*)(xl + (size_t)s * F1 + h * C1 + lane * 2);
            acc.x += w * v.x; acc.y += w * v.y;
        }
    }
    if (active) {
        float inv = 1.f / (ssum + 1e-16f);
        int c = h * C1 + lane * 2;
        float2 b = *(const float2*)(bias + c);
        float2 o;
        o.x = fmaxf(acc.x * inv + b.x, 0.f);
        o.y = fmaxf(acc.y * inv + b.y, 0.f);
        *(float2*)(hbuf + (size_t)node * F1 + c) = o;
    }
}

// ---------------- layer 2 ----------------

// one wave per node, dot over 960 with W2 [960,4]
__global__ void transform2(const float* __restrict__ hbuf,
                           const float* __restrict__ W2l, const float* __restrict__ W2r,
                           const float* __restrict__ b2l, const float* __restrict__ b2r,
                           float* __restrict__ xl2, float* __restrict__ xr2) {
    int wid = (blockIdx.x * blockDim.x + threadIdx.x) >> 6;
    int lane = threadIdx.x & 63;
    if (wid >= N_NODES) return;
    const float* hp = hbuf + (size_t)wid * F1;
    float al0=0, al1=0, al2=0, al3=0, ar0=0, ar1=0, ar2=0, ar3=0;
#pragma unroll
    for (int j = 0; j < F1 / 64; ++j) {
        int k = lane + 64 * j;
        float hv = hp[k];
        float4 wl = ((const float4*)W2l)[k];
        float4 wr = ((const float4*)W2r)[k];
        al0 += hv * wl.x; al1 += hv * wl.y; al2 += hv * wl.z; al3 += hv * wl.w;
        ar0 += hv * wr.x; ar1 += hv * wr.y; ar2 += hv * wr.z; ar3 += hv * wr.w;
    }
#pragma unroll
    for (int off = 32; off > 0; off >>= 1) {
        al0 += __shfl_down(al0, off, 64); al1 += __shfl_down(al1, off, 64);
        al2 += __shfl_down(al2, off, 64); al3 += __shfl_down(al3, off, 64);
        ar0 += __shfl_down(ar0, off, 64); ar1 += __shfl_down(ar1, off, 64);
        ar2 += __shfl_down(ar2, off, 64); ar3 += __shfl_down(ar3, off, 64);
    }
    if (lane == 0) {
        xl2[wid*4+0] = al0 + b2l[0]; xl2[wid*4+1] = al1 + b2l[1];
        xl2[wid*4+2] = al2 + b2l[2]; xl2[wid*4+3] = al3 + b2l[3];
        xr2[wid*4+0] = ar0 + b2r[0]; xr2[wid*4+1] = ar1 + b2r[1];
        xr2[wid*4+2] = ar2 + b2r[2]; xr2[wid*4+3] = ar3 + b2r[3];
    }
}

__global__ void logits2(const int* __restrict__ ei,
                        const float* __restrict__ xl2, const float* __restrict__ xr2,
                        const float* __restrict__ att2,
                        float* __restrict__ e2) {
    int e = blockIdx.x * blockDim.x + threadIdx.x;
    if (e >= E_TOT) return;
    int s, d; edge_sd(ei, e, s, d);
    float4 a = ((const float4*)xl2)[s];
    float4 b = ((const float4*)xr2)[d];
    float4 w = *(const float4*)att2;
    e2[e] = lrelu(a.x + b.x) * w.x + lrelu(a.y + b.y) * w.y
          + lrelu(a.z + b.z) * w.z + lrelu(a.w + b.w) * w.w;
}

// one wave per node: softmax + aggregate + bias
__global__ void softmax_agg2(const int* __restrict__ rowptr, const int* __restrict__ elist,
                             const int* __restrict__ ei,
                             const float* __restrict__ e2, const float* __restrict__ xl2,
                             const float* __restrict__ bias2,
                             float* __restrict__ out) {
    int node = (blockIdx.x * blockDim.x + threadIdx.x) >> 6;
    int lane = threadIdx.x & 63;
    if (node >= N_NODES) return;
    int beg = rowptr[node], end = rowptr[node + 1];

    float m = -INFINITY;
    for (int i = beg + lane; i < end; i += 64)
        m = fmaxf(m, e2[elist[i]]);
#pragma unroll
    for (int off = 32; off; off >>= 1) m = fmaxf(m, __shfl_xor(m, off, 64));

    float ssum = 0.f;
    float4 acc = {0.f, 0.f, 0.f, 0.f};
    for (int i = beg + lane; i < end; i += 64) {
        int e = elist[i];
        int s = edge_src(ei, e);
        float w = expf(e2[e] - m);
        ssum += w;
        float4 v = ((const float4*)xl2)[s];
        acc.x += w * v.x; acc.y += w * v.y; acc.z += w * v.z; acc.w += w * v.w;
    }
#pragma unroll
    for (int off = 32; off; off >>= 1) {
        ssum  += __shfl_xor(ssum,  off, 64);
        acc.x += __shfl_xor(acc.x, off, 64);
        acc.y += __shfl_xor(acc.y, off, 64);
        acc.z += __shfl_xor(acc.z, off, 64);
        acc.w += __shfl_xor(acc.w, off, 64);
    }
    if (lane == 0) {
        float inv = 1.f / (ssum + 1e-16f);
        out[node*4+0] = acc.x * inv + bias2[0];
        out[node*4+1] = acc.y * inv + bias2[1];
        out[node*4+2] = acc.z * inv + bias2[2];
        out[node*4+3] = acc.w * inv + bias2[3];
    }
}

extern "C" void kernel_launch(void* const* d_in, const int* in_sizes, int n_in,
                              void* d_out, int out_size, void* d_ws, size_t ws_size,
                              hipStream_t stream) {
    const float* x     = (const float*)d_in[0];
    const int*   ei    = (const int*)  d_in[1];
    const float* W1l   = (const float*)d_in[2];
    const float* W1r   = (const float*)d_in[3];
    const float* b1l   = (const float*)d_in[4];
    const float* b1r   = (const float*)d_in[5];
    const float* att1  = (const float*)d_in[6];
    const float* bias1 = (const float*)d_in[7];
    const float* W2l   = (const float*)d_in[8];
    const float* W2r   = (const float*)d_in[9];
    const float* b2l   = (const float*)d_in[10];
    const float* b2r   = (const float*)d_in[11];
    const float* att2  = (const float*)d_in[12];
    const float* bias2 = (const float*)d_in[13];
    float* out = (float*)d_out;

    // workspace carve-up (floats/ints)
    float* xl1  = (float*)d_ws;                           // N*F1
    float* xr1  = xl1 + (size_t)N_NODES * F1;             // N*F1 (reused as hbuf)
    float* hbuf = xr1;
    float* e1   = xr1 + (size_t)N_NODES * F1;             // E_TOT*H1
    float* xl2  = e1 + (size_t)E_TOT * H1;                // N*4
    float* xr2  = xl2 + N_NODES * 4;                      // N*4
    float* e2   = xr2 + N_NODES * 4;                      // E_TOT
    int*   deg    = (int*)(e2 + E_TOT);                   // N
    int*   rowptr = deg + N_NODES;                        // N+1
    int*   cur    = rowptr + N_NODES + 1;                 // N
    int*   elist  = cur + N_NODES;                        // E_TOT

    const int B = 256;

    hipMemsetAsync(deg, 0, N_NODES * sizeof(int), stream);

    transform1<<<(N_NODES * F1 + B - 1) / B, B, 0, stream>>>(x, W1l, W1r, b1l, b1r, xl1, xr1);
    deg_count<<<(E_TOT + B - 1) / B, B, 0, stream>>>(ei, deg);
    scan_rowptr<<<1, SCAN_T, 0, stream>>>(deg, rowptr, cur);
    fill_elist<<<(E_TOT + B - 1) / B, B, 0, stream>>>(ei, cur, elist);

    logits1<<<(E_TOT * H1 + B - 1) / B, B, 0, stream>>>(ei, xl1, xr1, att1, e1);
    softmax_agg1<<<((N_NODES * H1) * 64 + B - 1) / B, B, 0, stream>>>(rowptr, elist, ei, e1, xl1, bias1, hbuf);

    transform2<<<(N_NODES * 64 + B - 1) / B, B, 0, stream>>>(hbuf, W2l, W2r, b2l, b2r, xl2, xr2);
    logits2<<<(E_TOT + B - 1) / B, B, 0, stream>>>(ei, xl2, xr2, att2, e2);
    softmax_agg2<<<(N_NODES * 64 + B - 1) / B, B, 0, stream>>>(rowptr, elist, ei, e2, xl2, bias2, out);
}

// Round 3
// 193.115 us; speedup vs baseline: 46.0459x; 3.3715x over previous
//
#include <hip/hip_runtime.h>

#define N_NODES 10000
#define N_EDGES 160000
#define E_TOT   170000   // + self loops
#define H1      8
#define C1      120
#define F1      960      // H1*C1

__device__ __forceinline__ float lrelu(float v) { return v > 0.f ? v : 0.2f * v; }

__device__ __forceinline__ void edge_sd(const int* __restrict__ ei, int e, int& s, int& d) {
    if (e < N_EDGES) { s = ei[e]; d = ei[N_EDGES + e]; }
    else { s = e - N_EDGES; d = s; }
}
__device__ __forceinline__ int edge_src(const int* __restrict__ ei, int e) {
    return (e < N_EDGES) ? ei[e] : (e - N_EDGES);
}

// ---------------- CSR build (dst -> incoming edges) ----------------

__global__ void deg_count(const int* __restrict__ ei, int* __restrict__ deg) {
    int e = blockIdx.x * blockDim.x + threadIdx.x;
    if (e >= E_TOT) return;
    int s, d; edge_sd(ei, e, s, d);
    atomicAdd(&deg[d], 1);
}

#define SCAN_T 1024
#define SCAN_I 10   // SCAN_T*SCAN_I = 10240 >= N_NODES
__global__ void scan_rowptr(const int* __restrict__ deg,
                            int* __restrict__ rowptr, int* __restrict__ cur) {
    __shared__ int part[SCAN_T];
    int t = threadIdx.x;
    int base = t * SCAN_I;
    int vals[SCAN_I]; int sum = 0;
#pragma unroll
    for (int i = 0; i < SCAN_I; ++i) {
        int idx = base + i;
        vals[i] = (idx < N_NODES) ? deg[idx] : 0;
        sum += vals[i];
    }
    part[t] = sum;
    __syncthreads();
    for (int off = 1; off < SCAN_T; off <<= 1) {
        int v = (t >= off) ? part[t - off] : 0;
        __syncthreads();
        part[t] += v;
        __syncthreads();
    }
    int run = (t > 0) ? part[t - 1] : 0;  // exclusive base
#pragma unroll
    for (int i = 0; i < SCAN_I; ++i) {
        int idx = base + i;
        if (idx < N_NODES) { rowptr[idx] = run; cur[idx] = run; }
        run += vals[i];
    }
    if (t == SCAN_T - 1) rowptr[N_NODES] = run;
}

__global__ void fill_elist(const int* __restrict__ ei,
                           int* __restrict__ cur, int* __restrict__ elist) {
    int e = blockIdx.x * blockDim.x + threadIdx.x;
    if (e >= E_TOT) return;
    int s, d; edge_sd(ei, e, s, d);
    int pos = atomicAdd(&cur[d], 1);
    elist[pos] = e;
}

// ---------------- layer-1 logits computed directly from x (thread per edge) ----------------

#define LOG1_B 256
__global__ void logits1_direct(const int* __restrict__ ei, const float* __restrict__ x,
                               const float* __restrict__ W1l, const float* __restrict__ W1r,
                               const float* __restrict__ b1l, const float* __restrict__ b1r,
                               const float* __restrict__ att1,
                               float* __restrict__ e1) {
    __shared__ float4 Wlt[F1];   // transposed Wl: Wlt[c] = Wl[0..3][c]
    __shared__ float4 Wrt[F1];
    __shared__ float2 ba[F1];    // { b1l[c]+b1r[c], att1[c] }
    int tid = threadIdx.x;
    for (int c = tid; c < F1; c += LOG1_B) {
        Wlt[c] = make_float4(W1l[c], W1l[F1 + c], W1l[2*F1 + c], W1l[3*F1 + c]);
        Wrt[c] = make_float4(W1r[c], W1r[F1 + c], W1r[2*F1 + c], W1r[3*F1 + c]);
        ba[c]  = make_float2(b1l[c] + b1r[c], att1[c]);
    }
    __syncthreads();
    int e = blockIdx.x * LOG1_B + tid;
    if (e >= E_TOT) return;
    int s, d; edge_sd(ei, e, s, d);
    float4 xs = ((const float4*)x)[s];
    float4 xd = ((const float4*)x)[d];
#pragma unroll
    for (int h = 0; h < H1; ++h) {
        float a = 0.f;
#pragma unroll 4
        for (int c = h * C1; c < h * C1 + C1; ++c) {
            float4 wl = Wlt[c], wr = Wrt[c];
            float2 bt = ba[c];
            float t = bt.x + xs.x*wl.x + xs.y*wl.y + xs.z*wl.z + xs.w*wl.w
                           + xd.x*wr.x + xd.y*wr.y + xd.z*wr.z + xd.w*wr.w;
            a += bt.y * lrelu(t);
        }
        e1[(size_t)e * H1 + h] = a;
    }
}

// ---------------- layer-1 softmax + aggregate (in x-space) + expand + bias + relu ----------------
// one wave per node (4 nodes per 256-thread block); grid exactly N_NODES/4 blocks

__global__ void softmax_agg1(const int* __restrict__ rowptr, const int* __restrict__ elist,
                             const int* __restrict__ ei,
                             const float* __restrict__ e1, const float* __restrict__ x,
                             const float* __restrict__ W1l, const float* __restrict__ b1l,
                             const float* __restrict__ bias1,
                             float* __restrict__ hbuf) {
    __shared__ float4 Wlt[F1];
    __shared__ float  bl_s[F1], bias_s[F1];
    __shared__ float  aggs[4][H1 * 5];   // per wave: [h]{aggn.x,y,z,w, salpha}
    int tid = threadIdx.x;
    for (int c = tid; c < F1; c += 256) {
        Wlt[c] = make_float4(W1l[c], W1l[F1 + c], W1l[2*F1 + c], W1l[3*F1 + c]);
        bl_s[c] = b1l[c];
        bias_s[c] = bias1[c];
    }
    __syncthreads();

    int w = tid >> 6, lane = tid & 63;
    int node = blockIdx.x * 4 + w;   // grid sized exactly: node always < N_NODES
    int beg = rowptr[node], end = rowptr[node + 1];

    // pass A: per-head max over incoming edges
    float m[H1];
#pragma unroll
    for (int h = 0; h < H1; ++h) m[h] = -INFINITY;
    for (int i = beg + lane; i < end; i += 64) {
        int e = elist[i];
        const float4* p = (const float4*)(e1 + (size_t)e * H1);
        float4 ea = p[0], eb = p[1];
        m[0] = fmaxf(m[0], ea.x); m[1] = fmaxf(m[1], ea.y);
        m[2] = fmaxf(m[2], ea.z); m[3] = fmaxf(m[3], ea.w);
        m[4] = fmaxf(m[4], eb.x); m[5] = fmaxf(m[5], eb.y);
        m[6] = fmaxf(m[6], eb.z); m[7] = fmaxf(m[7], eb.w);
    }
#pragma unroll
    for (int off = 32; off; off >>= 1) {
#pragma unroll
        for (int h = 0; h < H1; ++h) m[h] = fmaxf(m[h], __shfl_xor(m[h], off, 64));
    }

    // pass B: weighted 4-dim aggregate per head + denominators
    float ssum[H1]; float4 ag[H1];
#pragma unroll
    for (int h = 0; h < H1; ++h) { ssum[h] = 0.f; ag[h] = make_float4(0.f, 0.f, 0.f, 0.f); }
    for (int i = beg + lane; i < end; i += 64) {
        int e = elist[i];
        int s = edge_src(ei, e);
        const float4* p = (const float4*)(e1 + (size_t)e * H1);
        float4 ea = p[0], eb = p[1];
        float4 xv = ((const float4*)x)[s];
        float ww;
        ww = __expf(ea.x - m[0]); ssum[0] += ww; ag[0].x += ww*xv.x; ag[0].y += ww*xv.y; ag[0].z += ww*xv.z; ag[0].w += ww*xv.w;
        ww = __expf(ea.y - m[1]); ssum[1] += ww; ag[1].x += ww*xv.x; ag[1].y += ww*xv.y; ag[1].z += ww*xv.z; ag[1].w += ww*xv.w;
        ww = __expf(ea.z - m[2]); ssum[2] += ww; ag[2].x += ww*xv.x; ag[2].y += ww*xv.y; ag[2].z += ww*xv.z; ag[2].w += ww*xv.w;
        ww = __expf(ea.w - m[3]); ssum[3] += ww; ag[3].x += ww*xv.x; ag[3].y += ww*xv.y; ag[3].z += ww*xv.z; ag[3].w += ww*xv.w;
        ww = __expf(eb.x - m[4]); ssum[4] += ww; ag[4].x += ww*xv.x; ag[4].y += ww*xv.y; ag[4].z += ww*xv.z; ag[4].w += ww*xv.w;
        ww = __expf(eb.y - m[5]); ssum[5] += ww; ag[5].x += ww*xv.x; ag[5].y += ww*xv.y; ag[5].z += ww*xv.z; ag[5].w += ww*xv.w;
        ww = __expf(eb.z - m[6]); ssum[6] += ww; ag[6].x += ww*xv.x; ag[6].y += ww*xv.y; ag[6].z += ww*xv.z; ag[6].w += ww*xv.w;
        ww = __expf(eb.w - m[7]); ssum[7] += ww; ag[7].x += ww*xv.x; ag[7].y += ww*xv.y; ag[7].z += ww*xv.z; ag[7].w += ww*xv.w;
    }
#pragma unroll
    for (int off = 32; off; off >>= 1) {
#pragma unroll
        for (int h = 0; h < H1; ++h) {
            ssum[h] += __shfl_xor(ssum[h], off, 64);
            ag[h].x += __shfl_xor(ag[h].x, off, 64);
            ag[h].y += __shfl_xor(ag[h].y, off, 64);
            ag[h].z += __shfl_xor(ag[h].z, off, 64);
            ag[h].w += __shfl_xor(ag[h].w, off, 64);
        }
    }
    if (lane == 0) {
#pragma unroll
        for (int h = 0; h < H1; ++h) {
            float inv = 1.f / (ssum[h] + 1e-16f);
            aggs[w][h*5+0] = ag[h].x * inv;
            aggs[w][h*5+1] = ag[h].y * inv;
            aggs[w][h*5+2] = ag[h].z * inv;
            aggs[w][h*5+3] = ag[h].w * inv;
            aggs[w][h*5+4] = ssum[h] * inv;   // sum of alphas (multiplies bl)
        }
    }
    __syncthreads();

    // expand: hbuf[node, c] = relu(aggn[h]·Wl[:,c] + salpha[h]*bl[c] + bias1[c])
    float* hp = hbuf + (size_t)node * F1;
#pragma unroll
    for (int j = 0; j < F1 / 64; ++j) {
        int c = lane + 64 * j;
        int h = c / C1;
        float4 wv = Wlt[c];
        float a0 = aggs[w][h*5+0], a1 = aggs[w][h*5+1];
        float a2 = aggs[w][h*5+2], a3 = aggs[w][h*5+3];
        float sa = aggs[w][h*5+4];
        float o = a0*wv.x + a1*wv.y + a2*wv.z + a3*wv.w + sa*bl_s[c] + bias_s[c];
        hp[c] = fmaxf(o, 0.f);
    }
}

// ---------------- layer 2 ----------------

// one wave per node, dot over 960 with W2 [960,4]
__global__ void transform2(const float* __restrict__ hbuf,
                           const float* __restrict__ W2l, const float* __restrict__ W2r,
                           const float* __restrict__ b2l, const float* __restrict__ b2r,
                           float* __restrict__ xl2, float* __restrict__ xr2) {
    int wid = (blockIdx.x * blockDim.x + threadIdx.x) >> 6;
    int lane = threadIdx.x & 63;
    if (wid >= N_NODES) return;
    const float* hp = hbuf + (size_t)wid * F1;
    float al0=0, al1=0, al2=0, al3=0, ar0=0, ar1=0, ar2=0, ar3=0;
#pragma unroll
    for (int j = 0; j < F1 / 64; ++j) {
        int k = lane + 64 * j;
        float hv = hp[k];
        float4 wl = ((const float4*)W2l)[k];
        float4 wr = ((const float4*)W2r)[k];
        al0 += hv * wl.x; al1 += hv * wl.y; al2 += hv * wl.z; al3 += hv * wl.w;
        ar0 += hv * wr.x; ar1 += hv * wr.y; ar2 += hv * wr.z; ar3 += hv * wr.w;
    }
#pragma unroll
    for (int off = 32; off > 0; off >>= 1) {
        al0 += __shfl_down(al0, off, 64); al1 += __shfl_down(al1, off, 64);
        al2 += __shfl_down(al2, off, 64); al3 += __shfl_down(al3, off, 64);
        ar0 += __shfl_down(ar0, off, 64); ar1 += __shfl_down(ar1, off, 64);
        ar2 += __shfl_down(ar2, off, 64); ar3 += __shfl_down(ar3, off, 64);
    }
    if (lane == 0) {
        xl2[wid*4+0] = al0 + b2l[0]; xl2[wid*4+1] = al1 + b2l[1];
        xl2[wid*4+2] = al2 + b2l[2]; xl2[wid*4+3] = al3 + b2l[3];
        xr2[wid*4+0] = ar0 + b2r[0]; xr2[wid*4+1] = ar1 + b2r[1];
        xr2[wid*4+2] = ar2 + b2r[2]; xr2[wid*4+3] = ar3 + b2r[3];
    }
}

__global__ void logits2(const int* __restrict__ ei,
                        const float* __restrict__ xl2, const float* __restrict__ xr2,
                        const float* __restrict__ att2,
                        float* __restrict__ e2) {
    int e = blockIdx.x * blockDim.x + threadIdx.x;
    if (e >= E_TOT) return;
    int s, d; edge_sd(ei, e, s, d);
    float4 a = ((const float4*)xl2)[s];
    float4 b = ((const float4*)xr2)[d];
    float4 w = *(const float4*)att2;
    e2[e] = lrelu(a.x + b.x) * w.x + lrelu(a.y + b.y) * w.y
          + lrelu(a.z + b.z) * w.z + lrelu(a.w + b.w) * w.w;
}

// one wave per node: softmax + aggregate + bias
__global__ void softmax_agg2(const int* __restrict__ rowptr, const int* __restrict__ elist,
                             const int* __restrict__ ei,
                             const float* __restrict__ e2, const float* __restrict__ xl2,
                             const float* __restrict__ bias2,
                             float* __restrict__ out) {
    int node = (blockIdx.x * blockDim.x + threadIdx.x) >> 6;
    int lane = threadIdx.x & 63;
    if (node >= N_NODES) return;
    int beg = rowptr[node], end = rowptr[node + 1];

    float m = -INFINITY;
    for (int i = beg + lane; i < end; i += 64)
        m = fmaxf(m, e2[elist[i]]);
#pragma unroll
    for (int off = 32; off; off >>= 1) m = fmaxf(m, __shfl_xor(m, off, 64));

    float ssum = 0.f;
    float4 acc = {0.f, 0.f, 0.f, 0.f};
    for (int i = beg + lane; i < end; i += 64) {
        int e = elist[i];
        int s = edge_src(ei, e);
        float w = __expf(e2[e] - m);
        ssum += w;
        float4 v = ((const float4*)xl2)[s];
        acc.x += w * v.x; acc.y += w * v.y; acc.z += w * v.z; acc.w += w * v.w;
    }
#pragma unroll
    for (int off = 32; off; off >>= 1) {
        ssum  += __shfl_xor(ssum,  off, 64);
        acc.x += __shfl_xor(acc.x, off, 64);
        acc.y += __shfl_xor(acc.y, off, 64);
        acc.z += __shfl_xor(acc.z, off, 64);
        acc.w += __shfl_xor(acc.w, off, 64);
    }
    if (lane == 0) {
        float inv = 1.f / (ssum + 1e-16f);
        out[node*4+0] = acc.x * inv + bias2[0];
        out[node*4+1] = acc.y * inv + bias2[1];
        out[node*4+2] = acc.z * inv + bias2[2];
        out[node*4+3] = acc.w * inv + bias2[3];
    }
}

extern "C" void kernel_launch(void* const* d_in, const int* in_sizes, int n_in,
                              void* d_out, int out_size, void* d_ws, size_t ws_size,
                              hipStream_t stream) {
    const float* x     = (const float*)d_in[0];
    const int*   ei    = (const int*)  d_in[1];
    const float* W1l   = (const float*)d_in[2];
    const float* W1r   = (const float*)d_in[3];
    const float* b1l   = (const float*)d_in[4];
    const float* b1r   = (const float*)d_in[5];
    const float* att1  = (const float*)d_in[6];
    const float* bias1 = (const float*)d_in[7];
    const float* W2l   = (const float*)d_in[8];
    const float* W2r   = (const float*)d_in[9];
    const float* b2l   = (const float*)d_in[10];
    const float* b2r   = (const float*)d_in[11];
    const float* att2  = (const float*)d_in[12];
    const float* bias2 = (const float*)d_in[13];
    float* out = (float*)d_out;

    // workspace carve-up
    float* hbuf = (float*)d_ws;                           // N*F1
    float* e1   = hbuf + (size_t)N_NODES * F1;            // E_TOT*H1
    float* xl2  = e1 + (size_t)E_TOT * H1;                // N*4
    float* xr2  = xl2 + N_NODES * 4;                      // N*4
    float* e2   = xr2 + N_NODES * 4;                      // E_TOT
    int*   deg    = (int*)(e2 + E_TOT);                   // N
    int*   rowptr = deg + N_NODES;                        // N+1
    int*   cur    = rowptr + N_NODES + 1;                 // N
    int*   elist  = cur + N_NODES;                        // E_TOT

    const int B = 256;

    hipMemsetAsync(deg, 0, N_NODES * sizeof(int), stream);
    deg_count<<<(E_TOT + B - 1) / B, B, 0, stream>>>(ei, deg);
    scan_rowptr<<<1, SCAN_T, 0, stream>>>(deg, rowptr, cur);
    fill_elist<<<(E_TOT + B - 1) / B, B, 0, stream>>>(ei, cur, elist);

    logits1_direct<<<(E_TOT + LOG1_B - 1) / LOG1_B, LOG1_B, 0, stream>>>(
        ei, x, W1l, W1r, b1l, b1r, att1, e1);
    softmax_agg1<<<N_NODES / 4, 256, 0, stream>>>(
        rowptr, elist, ei, e1, x, W1l, b1l, bias1, hbuf);

    transform2<<<(N_NODES * 64 + B - 1) / B, B, 0, stream>>>(hbuf, W2l, W2r, b2l, b2r, xl2, xr2);
    logits2<<<(E_TOT + B - 1) / B, B, 0, stream>>>(ei, xl2, xr2, att2, e2);
    softmax_agg2<<<(N_NODES * 64 + B - 1) / B, B, 0, stream>>>(rowptr, elist, ei, e2, xl2, bias2, out);
}

// Round 4
// 168.914 us; speedup vs baseline: 52.6431x; 1.1433x over previous
//
#include <hip/hip_runtime.h>

#define N_NODES 10000
#define N_EDGES 160000
#define E_TOT   170000   // + self loops
#define H1      8
#define C1      120
#define F1      960      // H1*C1

__device__ __forceinline__ float lrelu(float v) { return fmaxf(v, 0.2f * v); }

// ---------------- CSR build (dst -> incoming edges) ----------------

__global__ void deg_count(const int* __restrict__ ei, int* __restrict__ deg) {
    int e = blockIdx.x * blockDim.x + threadIdx.x;
    if (e >= E_TOT) return;
    int d = (e < N_EDGES) ? ei[N_EDGES + e] : (e - N_EDGES);
    atomicAdd(&deg[d], 1);
}

#define SCAN_T 1024
#define SCAN_I 10   // SCAN_T*SCAN_I = 10240 >= N_NODES
__global__ void scan_rowptr(const int* __restrict__ deg,
                            int* __restrict__ rowptr, int* __restrict__ cur) {
    __shared__ int part[SCAN_T];
    int t = threadIdx.x;
    int base = t * SCAN_I;
    int vals[SCAN_I]; int sum = 0;
#pragma unroll
    for (int i = 0; i < SCAN_I; ++i) {
        int idx = base + i;
        vals[i] = (idx < N_NODES) ? deg[idx] : 0;
        sum += vals[i];
    }
    part[t] = sum;
    __syncthreads();
    for (int off = 1; off < SCAN_T; off <<= 1) {
        int v = (t >= off) ? part[t - off] : 0;
        __syncthreads();
        part[t] += v;
        __syncthreads();
    }
    int run = (t > 0) ? part[t - 1] : 0;  // exclusive base
#pragma unroll
    for (int i = 0; i < SCAN_I; ++i) {
        int idx = base + i;
        if (idx < N_NODES) { rowptr[idx] = run; cur[idx] = run; }
        run += vals[i];
    }
    if (t == SCAN_T - 1) rowptr[N_NODES] = run;
}

// epos[e] = CSR slot of edge e; slist[slot] = src node
__global__ void fill_csr(const int* __restrict__ ei, int* __restrict__ cur,
                         int* __restrict__ epos, int* __restrict__ slist) {
    int e = blockIdx.x * blockDim.x + threadIdx.x;
    if (e >= E_TOT) return;
    int s, d;
    if (e < N_EDGES) { s = ei[e]; d = ei[N_EDGES + e]; } else { s = e - N_EDGES; d = s; }
    int pos = atomicAdd(&cur[d], 1);
    epos[e] = pos;
    slist[pos] = s;
}

// ---------------- layer-1 logits: scalar (SGPR) weights, head-pair per blockIdx.y ----------------
// grid: (ceil(E_TOT/256), 4).  All weight indices are wave-uniform -> s_load.

__global__ void logits1_scalar(const int* __restrict__ ei, const float* __restrict__ x,
                               const float* __restrict__ W1l, const float* __restrict__ W1r,
                               const float* __restrict__ b1l, const float* __restrict__ b1r,
                               const float* __restrict__ att1, const int* __restrict__ epos,
                               float* __restrict__ e1) {
    int e = blockIdx.x * 256 + threadIdx.x;
    if (e >= E_TOT) return;
    int s, d;
    if (e < N_EDGES) { s = ei[e]; d = ei[N_EDGES + e]; } else { s = e - N_EDGES; d = s; }
    float4 xs = ((const float4*)x)[s];
    float4 xd = ((const float4*)x)[d];
    int hg = blockIdx.y;           // uniform head pair {2hg, 2hg+1}
    float acc0 = 0.f, acc1 = 0.f;
#pragma unroll
    for (int hh = 0; hh < 2; ++hh) {
        int cb = (hg * 2 + hh) * C1;   // uniform
        float acc = 0.f;
#pragma unroll 4
        for (int u = 0; u < C1; ++u) {
            int c = cb + u;            // uniform
            float t = b1l[c] + b1r[c]
                    + xs.x * W1l[c]        + xs.y * W1l[F1 + c]
                    + xs.z * W1l[2*F1 + c] + xs.w * W1l[3*F1 + c]
                    + xd.x * W1r[c]        + xd.y * W1r[F1 + c]
                    + xd.z * W1r[2*F1 + c] + xd.w * W1r[3*F1 + c];
            acc = fmaf(att1[c], lrelu(t), acc);
        }
        if (hh == 0) acc0 = acc; else acc1 = acc;
    }
    float2 o = make_float2(acc0, acc1);
    *(float2*)(e1 + (size_t)epos[e] * H1 + hg * 2) = o;   // CSR-ordered
}

// ---------------- layer-1 softmax + aggregate(x-space) + expand + relu + layer-2 transform ----------------
// one wave per node; block = 4 waves; grid = N_NODES/4

__global__ void fused_agg1(const int* __restrict__ rowptr, const int* __restrict__ slist,
                           const float* __restrict__ e1, const float* __restrict__ x,
                           const float* __restrict__ W1l, const float* __restrict__ b1l,
                           const float* __restrict__ bias1,
                           const float* __restrict__ W2l, const float* __restrict__ W2r,
                           const float* __restrict__ b2l, const float* __restrict__ b2r,
                           float* __restrict__ xl2, float* __restrict__ xr2) {
    __shared__ float4 Wlt[F1];   // 15.4 KB transposed Wl
    int tid = threadIdx.x;
    for (int c = tid; c < F1; c += 256)
        Wlt[c] = make_float4(W1l[c], W1l[F1 + c], W1l[2*F1 + c], W1l[3*F1 + c]);
    __syncthreads();

    int node = blockIdx.x * 4 + (tid >> 6);
    int lane = tid & 63;
    int beg = rowptr[node], end = rowptr[node + 1];

    // pass A: per-head max (e1 reads coalesced: CSR order)
    float m[H1];
#pragma unroll
    for (int h = 0; h < H1; ++h) m[h] = -1e30f;
    for (int i = beg + lane; i < end; i += 64) {
        const float4* p = (const float4*)(e1 + (size_t)i * H1);
        float4 ea = p[0], eb = p[1];
        m[0] = fmaxf(m[0], ea.x); m[1] = fmaxf(m[1], ea.y);
        m[2] = fmaxf(m[2], ea.z); m[3] = fmaxf(m[3], ea.w);
        m[4] = fmaxf(m[4], eb.x); m[5] = fmaxf(m[5], eb.y);
        m[6] = fmaxf(m[6], eb.z); m[7] = fmaxf(m[7], eb.w);
    }
#pragma unroll
    for (int off = 32; off; off >>= 1)
#pragma unroll
        for (int h = 0; h < H1; ++h) m[h] = fmaxf(m[h], __shfl_xor(m[h], off, 64));

    // pass B: weighted 4-dim aggregate + denominators
    float ssum[H1]; float4 ag[H1];
#pragma unroll
    for (int h = 0; h < H1; ++h) { ssum[h] = 0.f; ag[h] = make_float4(0.f, 0.f, 0.f, 0.f); }
    for (int i = beg + lane; i < end; i += 64) {
        const float4* p = (const float4*)(e1 + (size_t)i * H1);
        float4 ea = p[0], eb = p[1];
        float4 xv = ((const float4*)x)[slist[i]];
        float w;
        w = __expf(ea.x - m[0]); ssum[0] += w; ag[0].x += w*xv.x; ag[0].y += w*xv.y; ag[0].z += w*xv.z; ag[0].w += w*xv.w;
        w = __expf(ea.y - m[1]); ssum[1] += w; ag[1].x += w*xv.x; ag[1].y += w*xv.y; ag[1].z += w*xv.z; ag[1].w += w*xv.w;
        w = __expf(ea.z - m[2]); ssum[2] += w; ag[2].x += w*xv.x; ag[2].y += w*xv.y; ag[2].z += w*xv.z; ag[2].w += w*xv.w;
        w = __expf(ea.w - m[3]); ssum[3] += w; ag[3].x += w*xv.x; ag[3].y += w*xv.y; ag[3].z += w*xv.z; ag[3].w += w*xv.w;
        w = __expf(eb.x - m[4]); ssum[4] += w; ag[4].x += w*xv.x; ag[4].y += w*xv.y; ag[4].z += w*xv.z; ag[4].w += w*xv.w;
        w = __expf(eb.y - m[5]); ssum[5] += w; ag[5].x += w*xv.x; ag[5].y += w*xv.y; ag[5].z += w*xv.z; ag[5].w += w*xv.w;
        w = __expf(eb.z - m[6]); ssum[6] += w; ag[6].x += w*xv.x; ag[6].y += w*xv.y; ag[6].z += w*xv.z; ag[6].w += w*xv.w;
        w = __expf(eb.w - m[7]); ssum[7] += w; ag[7].x += w*xv.x; ag[7].y += w*xv.y; ag[7].z += w*xv.z; ag[7].w += w*xv.w;
    }
#pragma unroll
    for (int off = 32; off; off >>= 1)
#pragma unroll
        for (int h = 0; h < H1; ++h) {
            ssum[h] += __shfl_xor(ssum[h], off, 64);
            ag[h].x += __shfl_xor(ag[h].x, off, 64);
            ag[h].y += __shfl_xor(ag[h].y, off, 64);
            ag[h].z += __shfl_xor(ag[h].z, off, 64);
            ag[h].w += __shfl_xor(ag[h].w, off, 64);
        }
    // normalize in-register (sa = sum of alphas, multiplies b1l)
#pragma unroll
    for (int h = 0; h < H1; ++h) {
        float inv = 1.f / (ssum[h] + 1e-16f);
        ag[h].x *= inv; ag[h].y *= inv; ag[h].z *= inv; ag[h].w *= inv;
        ssum[h] *= inv;
    }

    // expand to 960 channels in-register, fused with layer-2 dot (h static -> no dynamic indexing)
    float al0=0, al1=0, al2=0, al3=0, ar0=0, ar1=0, ar2=0, ar3=0;
#pragma unroll
    for (int h = 0; h < H1; ++h) {
#pragma unroll
        for (int rep = 0; rep < 2; ++rep) {
            int cl = rep * 64 + lane;
            if (cl < C1) {
                int c = h * C1 + cl;
                float4 wv = Wlt[c];
                float hb = ag[h].x*wv.x + ag[h].y*wv.y + ag[h].z*wv.z + ag[h].w*wv.w
                         + ssum[h]*b1l[c] + bias1[c];
                hb = fmaxf(hb, 0.f);
                float4 wa = ((const float4*)W2l)[c];
                float4 wb = ((const float4*)W2r)[c];
                al0 += hb*wa.x; al1 += hb*wa.y; al2 += hb*wa.z; al3 += hb*wa.w;
                ar0 += hb*wb.x; ar1 += hb*wb.y; ar2 += hb*wb.z; ar3 += hb*wb.w;
            }
        }
    }
#pragma unroll
    for (int off = 32; off; off >>= 1) {
        al0 += __shfl_xor(al0, off, 64); al1 += __shfl_xor(al1, off, 64);
        al2 += __shfl_xor(al2, off, 64); al3 += __shfl_xor(al3, off, 64);
        ar0 += __shfl_xor(ar0, off, 64); ar1 += __shfl_xor(ar1, off, 64);
        ar2 += __shfl_xor(ar2, off, 64); ar3 += __shfl_xor(ar3, off, 64);
    }
    if (lane == 0) {
        ((float4*)xl2)[node] = make_float4(al0 + b2l[0], al1 + b2l[1], al2 + b2l[2], al3 + b2l[3]);
        ((float4*)xr2)[node] = make_float4(ar0 + b2r[0], ar1 + b2r[1], ar2 + b2r[2], ar3 + b2r[3]);
    }
}

// ---------------- layer-2 logits + softmax + aggregate + bias, fused; one wave per node ----------------

__global__ void attn2(const int* __restrict__ rowptr, const int* __restrict__ slist,
                      const float* __restrict__ xl2, const float* __restrict__ xr2,
                      const float* __restrict__ att2, const float* __restrict__ bias2,
                      float* __restrict__ out) {
    int node = blockIdx.x * 4 + (threadIdx.x >> 6);
    int lane = threadIdx.x & 63;
    int beg = rowptr[node], end = rowptr[node + 1];
    float4 xr = ((const float4*)xr2)[node];
    float4 aw = make_float4(att2[0], att2[1], att2[2], att2[3]);   // uniform

    // pass A: logits (cache first 2 per lane), max
    float l0 = -1e30f, l1 = -1e30f;
    float4 c0 = make_float4(0,0,0,0), c1 = make_float4(0,0,0,0);
    int i0 = beg + lane;
    if (i0 < end) {
        c0 = ((const float4*)xl2)[slist[i0]];
        l0 = aw.x*lrelu(c0.x+xr.x) + aw.y*lrelu(c0.y+xr.y) + aw.z*lrelu(c0.z+xr.z) + aw.w*lrelu(c0.w+xr.w);
    }
    if (i0 + 64 < end) {
        c1 = ((const float4*)xl2)[slist[i0 + 64]];
        l1 = aw.x*lrelu(c1.x+xr.x) + aw.y*lrelu(c1.y+xr.y) + aw.z*lrelu(c1.z+xr.z) + aw.w*lrelu(c1.w+xr.w);
    }
    float m = fmaxf(l0, l1);
    for (int i = i0 + 128; i < end; i += 64) {   // rare overflow (deg > 128)
        float4 xv = ((const float4*)xl2)[slist[i]];
        float lg = aw.x*lrelu(xv.x+xr.x) + aw.y*lrelu(xv.y+xr.y) + aw.z*lrelu(xv.z+xr.z) + aw.w*lrelu(xv.w+xr.w);
        m = fmaxf(m, lg);
    }
#pragma unroll
    for (int off = 32; off; off >>= 1) m = fmaxf(m, __shfl_xor(m, off, 64));

    // pass B
    float ssum = 0.f;
    float4 acc = make_float4(0,0,0,0);
    if (i0 < end) {
        float w = __expf(l0 - m); ssum += w;
        acc.x += w*c0.x; acc.y += w*c0.y; acc.z += w*c0.z; acc.w += w*c0.w;
    }
    if (i0 + 64 < end) {
        float w = __expf(l1 - m); ssum += w;
        acc.x += w*c1.x; acc.y += w*c1.y; acc.z += w*c1.z; acc.w += w*c1.w;
    }
    for (int i = i0 + 128; i < end; i += 64) {
        float4 xv = ((const float4*)xl2)[slist[i]];
        float lg = aw.x*lrelu(xv.x+xr.x) + aw.y*lrelu(xv.y+xr.y) + aw.z*lrelu(xv.z+xr.z) + aw.w*lrelu(xv.w+xr.w);
        float w = __expf(lg - m); ssum += w;
        acc.x += w*xv.x; acc.y += w*xv.y; acc.z += w*xv.z; acc.w += w*xv.w;
    }
#pragma unroll
    for (int off = 32; off; off >>= 1) {
        ssum  += __shfl_xor(ssum,  off, 64);
        acc.x += __shfl_xor(acc.x, off, 64);
        acc.y += __shfl_xor(acc.y, off, 64);
        acc.z += __shfl_xor(acc.z, off, 64);
        acc.w += __shfl_xor(acc.w, off, 64);
    }
    if (lane == 0) {
        float inv = 1.f / (ssum + 1e-16f);
        out[node*4+0] = acc.x * inv + bias2[0];
        out[node*4+1] = acc.y * inv + bias2[1];
        out[node*4+2] = acc.z * inv + bias2[2];
        out[node*4+3] = acc.w * inv + bias2[3];
    }
}

extern "C" void kernel_launch(void* const* d_in, const int* in_sizes, int n_in,
                              void* d_out, int out_size, void* d_ws, size_t ws_size,
                              hipStream_t stream) {
    const float* x     = (const float*)d_in[0];
    const int*   ei    = (const int*)  d_in[1];
    const float* W1l   = (const float*)d_in[2];
    const float* W1r   = (const float*)d_in[3];
    const float* b1l   = (const float*)d_in[4];
    const float* b1r   = (const float*)d_in[5];
    const float* att1  = (const float*)d_in[6];
    const float* bias1 = (const float*)d_in[7];
    const float* W2l   = (const float*)d_in[8];
    const float* W2r   = (const float*)d_in[9];
    const float* b2l   = (const float*)d_in[10];
    const float* b2r   = (const float*)d_in[11];
    const float* att2  = (const float*)d_in[12];
    const float* bias2 = (const float*)d_in[13];
    float* out = (float*)d_out;

    // workspace carve-up
    float* e1   = (float*)d_ws;                  // E_TOT*8 (CSR-ordered logits)
    float* xl2  = e1 + (size_t)E_TOT * H1;       // N*4
    float* xr2  = xl2 + N_NODES * 4;             // N*4
    int* deg    = (int*)(xr2 + N_NODES * 4);     // N
    int* rowptr = deg + N_NODES;                 // N+1
    int* cur    = rowptr + N_NODES + 1;          // N
    int* epos   = cur + N_NODES;                 // E_TOT
    int* slist  = epos + E_TOT;                  // E_TOT

    const int B = 256;

    hipMemsetAsync(deg, 0, N_NODES * sizeof(int), stream);
    deg_count<<<(E_TOT + B - 1) / B, B, 0, stream>>>(ei, deg);
    scan_rowptr<<<1, SCAN_T, 0, stream>>>(deg, rowptr, cur);
    fill_csr<<<(E_TOT + B - 1) / B, B, 0, stream>>>(ei, cur, epos, slist);

    logits1_scalar<<<dim3((E_TOT + B - 1) / B, 4), B, 0, stream>>>(
        ei, x, W1l, W1r, b1l, b1r, att1, epos, e1);
    fused_agg1<<<N_NODES / 4, B, 0, stream>>>(
        rowptr, slist, e1, x, W1l, b1l, bias1, W2l, W2r, b2l, b2r, xl2, xr2);
    attn2<<<N_NODES / 4, B, 0, stream>>>(rowptr, slist, xl2, xr2, att2, bias2, out);
}